// Round 4
// baseline (17758.063 us; speedup 1.0000x reference)
//
#include <hip/hip_runtime.h>
#include <hip/hip_bf16.h>

// PGN decoder: B=32, L=400, T=40 steps, H=A=512, E=256, V=32000, oov=50.
// Outputs (flat in d_out, fp32): final (40,32,32050) | attns (40,32,400) |
// covs (40,32,400) | h_f (32,512) | ctx_f (32,512) | pgens (40,32)
#define VV 32000
#define VEXT 32050
#define NBLK 256u
// NBLK=256 with static LDS 33792B (>32KiB) + regular launch: per-CU capacity is
// >=1 block, so 256 blocks <= 256 CUs * capacity => all blocks resident => the
// software grid barrier is deadlock-free. (Cooperative API failed silently in R3.)

typedef __attribute__((ext_vector_type(8))) short bf16x8;
typedef __attribute__((ext_vector_type(4))) float f32x4;
typedef __attribute__((ext_vector_type(2))) float f32x2;

__device__ __forceinline__ float bf2f(unsigned short u){
  union { unsigned int i; float f; } v; v.i = ((unsigned int)u) << 16; return v.f;
}
__device__ __forceinline__ unsigned short f2bf(float f){
  union { float f; unsigned int i; } v; v.f = f;
  unsigned int i = v.i;
  return (unsigned short)((i + 0x7FFFu + ((i >> 16) & 1u)) >> 16); // RNE
}
__device__ __forceinline__ float fast_tanh(float x){
  x = fminf(20.f, fmaxf(-20.f, x));
  float e = __expf(2.f * x);
  return (e - 1.f) * __builtin_amdgcn_rcpf(e + 1.f);
}
__device__ __forceinline__ float fast_sigmoid(float x){
  x = fminf(30.f, fmaxf(-30.f, x));
  return __builtin_amdgcn_rcpf(1.f + __expf(-x));
}

// ---------------- grid barrier (all NBLK blocks must call) ----------------
__device__ __forceinline__ void gbar(unsigned* bar, unsigned& ep){
  __threadfence();
  __syncthreads();
  if (threadIdx.x == 0){
    unsigned old = __hip_atomic_fetch_add(&bar[0], 1u, __ATOMIC_ACQ_REL, __HIP_MEMORY_SCOPE_AGENT);
    if (old == NBLK - 1u){
      __hip_atomic_store(&bar[0], 0u, __ATOMIC_RELAXED, __HIP_MEMORY_SCOPE_AGENT);
      __hip_atomic_fetch_add(&bar[1], 1u, __ATOMIC_RELEASE, __HIP_MEMORY_SCOPE_AGENT);
    } else {
      while (__hip_atomic_load(&bar[1], __ATOMIC_ACQUIRE, __HIP_MEMORY_SCOPE_AGENT) <= ep){
        __builtin_amdgcn_s_sleep(2);
      }
    }
    ep++;
  }
  __syncthreads();
  __threadfence();
}

// ---------------- device units ----------------
__device__ void gru_block(int blk, int tid, unsigned short* xs,
    const float* __restrict__ ctx_old, const float* __restrict__ h_old,
    const float* __restrict__ embW_t,
    const unsigned short* __restrict__ WgT, const unsigned short* __restrict__ UgT,
    float* __restrict__ h_new, unsigned short* __restrict__ h_new_bf, float* hf_out)
{
  for (int i = tid; i < 32 * 512; i += 256){
    int bb = i >> 9, c = i & 511;
    xs[bb * 520 + c] = f2bf(ctx_old[i]);
  }
  __syncthreads();
  int lane = tid & 63, w = tid >> 6;
  int l15 = lane & 15, quad = lane >> 4;
  int mt = (w & 1) * 16;
  int n0 = blk * 64 + (w >> 1) * 32;
  f32x4 accZ[2], accR[2], accH[2], accU[2];
  #pragma unroll
  for (int s = 0; s < 2; s++){
    int col = n0 + s * 16 + l15;
    #pragma unroll
    for (int r = 0; r < 4; r++){
      int row = mt + quad * 4 + r;
      const float* e = embW_t + (size_t)row * 1536 + col;
      accZ[s][r] = e[0]; accR[s][r] = e[512]; accH[s][r] = e[1024];
      accU[s][r] = 0.f;
    }
  }
  for (int k0 = 0; k0 < 512; k0 += 32){
    bf16x8 a = *(const bf16x8*)(xs + (mt + l15) * 520 + k0 + quad * 8);
    #pragma unroll
    for (int s = 0; s < 2; s++){
      int col = n0 + s * 16 + l15;
      const unsigned short* bz = WgT + (size_t)col * 768 + 256 + k0 + quad * 8;
      const unsigned short* br = WgT + (size_t)(col + 512) * 768 + 256 + k0 + quad * 8;
      const unsigned short* bh = WgT + (size_t)(col + 1024) * 768 + 256 + k0 + quad * 8;
      accZ[s] = __builtin_amdgcn_mfma_f32_16x16x32_bf16(a, *(const bf16x8*)bz, accZ[s], 0, 0, 0);
      accR[s] = __builtin_amdgcn_mfma_f32_16x16x32_bf16(a, *(const bf16x8*)br, accR[s], 0, 0, 0);
      accH[s] = __builtin_amdgcn_mfma_f32_16x16x32_bf16(a, *(const bf16x8*)bh, accH[s], 0, 0, 0);
    }
  }
  __syncthreads();
  for (int i = tid; i < 32 * 512; i += 256){
    int bb = i >> 9, c = i & 511;
    xs[bb * 520 + c] = f2bf(h_old[i]);
  }
  __syncthreads();
  for (int k0 = 0; k0 < 512; k0 += 32){
    bf16x8 a = *(const bf16x8*)(xs + (mt + l15) * 520 + k0 + quad * 8);
    #pragma unroll
    for (int s = 0; s < 2; s++){
      int col = n0 + s * 16 + l15;
      const unsigned short* bz = UgT + (size_t)col * 512 + k0 + quad * 8;
      const unsigned short* br = UgT + (size_t)(col + 512) * 512 + k0 + quad * 8;
      const unsigned short* bh = UgT + (size_t)(col + 1024) * 512 + k0 + quad * 8;
      accZ[s] = __builtin_amdgcn_mfma_f32_16x16x32_bf16(a, *(const bf16x8*)bz, accZ[s], 0, 0, 0);
      accR[s] = __builtin_amdgcn_mfma_f32_16x16x32_bf16(a, *(const bf16x8*)br, accR[s], 0, 0, 0);
      accU[s] = __builtin_amdgcn_mfma_f32_16x16x32_bf16(a, *(const bf16x8*)bh, accU[s], 0, 0, 0);
    }
  }
  #pragma unroll
  for (int s = 0; s < 2; s++){
    int col = n0 + s * 16 + l15;
    #pragma unroll
    for (int r = 0; r < 4; r++){
      int bb = mt + quad * 4 + r;
      float z  = fast_sigmoid(accZ[s][r]);
      float rr = fast_sigmoid(accR[s][r]);
      float hh = fast_tanh(accH[s][r] + rr * accU[s][r]);
      float ho = h_old[bb * 512 + col];
      float hn = z * ho + (1.f - z) * hh;
      h_new[bb * 512 + col] = hn;
      h_new_bf[bb * 512 + col] = f2bf(hn);
      if (hf_out) hf_out[bb * 512 + col] = hn;
    }
  }
  __syncthreads();
}

__device__ void gemm_unit(int tid, unsigned short* hs, float* smp,
    const unsigned short* __restrict__ h_bf, const unsigned short* __restrict__ Bm,
    const float* __restrict__ bias, float* __restrict__ out, int ldo, int n0,
    float* __restrict__ tilems_blk)
{
  for (int i = tid; i < 8192; i += 256){
    int bb = i >> 8;
    int cp = (i & 255) * 2;
    *(unsigned int*)(hs + bb * 520 + cp) = *(const unsigned int*)(h_bf + bb * 512 + cp);
  }
  __syncthreads();
  int lane = tid & 63, w = tid >> 6;
  int l15 = lane & 15, quad = lane >> 4;
  int mt = (w & 1) * 16;
  int nbase = n0 + (w >> 1) * 32;
  f32x4 acc[2];
  acc[0] = (f32x4)0.0f; acc[1] = (f32x4)0.0f;
  const unsigned short* arow = hs + (mt + l15) * 520 + quad * 8;
  for (int k0 = 0; k0 < 512; k0 += 32){
    bf16x8 a = *(const bf16x8*)(arow + k0);
    #pragma unroll
    for (int s = 0; s < 2; s++){
      const unsigned short* br = Bm + (size_t)(nbase + s * 16 + l15) * 512 + k0 + quad * 8;
      acc[s] = __builtin_amdgcn_mfma_f32_16x16x32_bf16(a, *(const bf16x8*)br, acc[s], 0, 0, 0);
    }
  }
  float vv[2][4];
  #pragma unroll
  for (int s = 0; s < 2; s++){
    int col = nbase + s * 16 + l15;
    float bi = bias[col];
    #pragma unroll
    for (int r = 0; r < 4; r++){
      int row = mt + quad * 4 + r;
      vv[s][r] = acc[s][r] + bi;
      out[(size_t)row * ldo + col] = vv[s][r];
    }
  }
  if (tilems_blk){
    #pragma unroll
    for (int r = 0; r < 4; r++){
      float m = fmaxf(vv[0][r], vv[1][r]);
      m = fmaxf(m, __shfl_xor(m, 1)); m = fmaxf(m, __shfl_xor(m, 2));
      m = fmaxf(m, __shfl_xor(m, 4)); m = fmaxf(m, __shfl_xor(m, 8));
      float e = __expf(vv[0][r] - m) + __expf(vv[1][r] - m);
      e += __shfl_xor(e, 1); e += __shfl_xor(e, 2); e += __shfl_xor(e, 4); e += __shfl_xor(e, 8);
      if (l15 == 0){
        smp[(w * 16 + quad * 4 + r) * 2]     = m;
        smp[(w * 16 + quad * 4 + r) * 2 + 1] = e;
      }
    }
    __syncthreads();
    if (tid < 32){
      int half = tid >> 4, row = tid & 15;
      float ma = smp[(half * 16 + row) * 2], mb = smp[((half + 2) * 16 + row) * 2];
      float M = fmaxf(ma, mb);
      float S = smp[(half * 16 + row) * 2 + 1] * __expf(ma - M)
              + smp[((half + 2) * 16 + row) * 2 + 1] * __expf(mb - M);
      tilems_blk[(half * 16 + row) * 2]     = M;
      tilems_blk[(half * 16 + row) * 2 + 1] = S;
    }
  }
  __syncthreads();
}

__device__ void score_unit(int b, int lt, int tid, float* sm,
    const unsigned short* __restrict__ ef_bf, const float* __restrict__ w1h,
    const float* __restrict__ Wc, const float* __restrict__ Va, const float* __restrict__ bv,
    const float* __restrict__ cov, float* __restrict__ scores)
{
  float* whs = sm; float* wcs = sm + 512; float* vas = sm + 1024;
  __syncthreads();
  for (int i = tid; i < 512; i += 256){ whs[i] = w1h[b * 512 + i]; wcs[i] = Wc[i]; vas[i] = Va[i]; }
  __syncthreads();
  int li = tid >> 4;
  int a0 = (tid & 15) * 32;
  int l = lt * 16 + li;
  float covl = cov ? cov[b * 400 + l] : 0.f;
  const unsigned short* ef = ef_bf + (size_t)(b * 400 + l) * 512 + a0;
  float p = 0.f;
  #pragma unroll
  for (int i = 0; i < 32; i += 8){
    bf16x8 v8 = *(const bf16x8*)(ef + i);
    #pragma unroll
    for (int j = 0; j < 8; j++){
      int aa = a0 + i + j;
      float arg = whs[aa] + bf2f((unsigned short)v8[j]) + covl * wcs[aa];
      p += fast_tanh(arg) * vas[aa];
    }
  }
  p += __shfl_xor(p, 1); p += __shfl_xor(p, 2); p += __shfl_xor(p, 4); p += __shfl_xor(p, 8);
  if ((tid & 15) == 0) scores[b * 400 + l] = p + bv[0];
}

__device__ void pgen_hd_unit(int b, int tid, float* red,
    const float* __restrict__ h_new, const float* __restrict__ Wp, float* pgen_hd)
{
  __syncthreads();
  float p = 0.f;
  for (int i = tid; i < 512; i += 256) p += h_new[b * 512 + i] * Wp[512 + i];
  red[tid] = p; __syncthreads();
  for (int s = 128; s > 0; s >>= 1){ if (tid < s) red[tid] += red[tid + s]; __syncthreads(); }
  if (tid == 0) pgen_hd[b] = red[0];
  __syncthreads();
}

__device__ void rowms_unit(int b, int tid, float* red,
    const float* __restrict__ tilems, float* rowMS)
{
  __syncthreads();
  float M = -1e30f;
  for (int i = tid; i < 500; i += 256) M = fmaxf(M, tilems[(i * 32 + b) * 2]);
  red[tid] = M; __syncthreads();
  for (int s = 128; s > 0; s >>= 1){ if (tid < s) red[tid] = fmaxf(red[tid], red[tid + s]); __syncthreads(); }
  M = red[0]; __syncthreads();
  float S = 0.f;
  for (int i = tid; i < 500; i += 256) S += tilems[(i * 32 + b) * 2 + 1] * __expf(tilems[(i * 32 + b) * 2] - M);
  red[tid] = S; __syncthreads();
  for (int s = 128; s > 0; s >>= 1){ if (tid < s) red[tid] += red[tid + s]; __syncthreads(); }
  if (tid == 0){ rowMS[b * 2] = M; rowMS[b * 2 + 1] = red[0]; }
  __syncthreads();
}

__device__ void attn_ctx_unit(int b, int ct, int tid, float* at, float* red,
    const float* __restrict__ scores, const float* __restrict__ mask,
    const float* __restrict__ cov_in, float* attn_out, float* cov_out,
    const unsigned short* __restrict__ enc_bf,
    float* __restrict__ ctx_out, float* ctxf_out, const float* __restrict__ Wp,
    float* __restrict__ pgen_cn, float* __restrict__ pgen_co)
{
  float mx = -1e30f;
  for (int i = tid; i < 400; i += 256){ float s = scores[b * 400 + i]; at[i] = s; mx = fmaxf(mx, s); }
  red[tid] = mx; __syncthreads();
  for (int s = 128; s > 0; s >>= 1){ if (tid < s) red[tid] = fmaxf(red[tid], red[tid + s]); __syncthreads(); }
  mx = red[0]; __syncthreads();
  float sm = 0.f;
  for (int i = tid; i < 400; i += 256){ float e = __expf(at[i] - mx) * mask[b * 400 + i]; at[i] = e; sm += e; }
  red[tid] = sm; __syncthreads();
  for (int s = 128; s > 0; s >>= 1){ if (tid < s) red[tid] += red[tid + s]; __syncthreads(); }
  float inv = __builtin_amdgcn_rcpf(red[0]);
  __syncthreads();
  for (int i = tid; i < 400; i += 256){
    float a = at[i] * inv; at[i] = a;
    if (ct == 0){
      if (attn_out) attn_out[b * 400 + i] = a;
      float cv = (cov_in ? cov_in[b * 400 + i] : 0.f) + a;
      if (cov_out) cov_out[b * 400 + i] = cv;
    }
  }
  __syncthreads();
  int colp = (tid & 31) * 2;
  int chunk = tid >> 5;
  const unsigned short* base = enc_bf + (size_t)b * 400 * 512 + ct * 64 + colp;
  float a0 = 0.f, a1 = 0.f;
  for (int i = 0; i < 50; i++){
    int l = chunk * 50 + i;
    unsigned int u = *(const unsigned int*)(base + (size_t)l * 512);
    float av = at[l];
    a0 += av * bf2f((unsigned short)(u & 0xffffu));
    a1 += av * bf2f((unsigned short)(u >> 16));
  }
  red[chunk * 64 + colp] = a0; red[chunk * 64 + colp + 1] = a1;
  __syncthreads();
  if (tid < 64){
    float s = 0.f;
    #pragma unroll
    for (int c = 0; c < 8; c++) s += red[c * 64 + tid];
    int col = ct * 64 + tid;
    ctx_out[b * 512 + col] = s;
    if (ctxf_out) ctxf_out[b * 512 + col] = s;
    float cn = s * Wp[col];
    float co = s * Wp[1280 + col];
    #pragma unroll
    for (int off = 32; off > 0; off >>= 1){ cn += __shfl_down(cn, off); co += __shfl_down(co, off); }
    if (tid == 0){ pgen_cn[b * 8 + ct] = cn; pgen_co[b * 8 + ct] = co; }
  }
  __syncthreads();
}

__device__ void final_dist_write(int f, int tid, float* s_pg,
    const float* __restrict__ logits, const float* __restrict__ rowMS,
    const float* __restrict__ pgen_hd, const float* __restrict__ pgen_cn,
    const float* __restrict__ pgen_co, const float* __restrict__ pgen_emb_t,
    const float* __restrict__ bp, float* __restrict__ final_t, float* __restrict__ pgens_t)
{
  int b = f >> 4, vt = f & 15;
  if (tid == 0){
    float pr = pgen_hd[b] + pgen_emb_t[b] + bp[0];
    #pragma unroll
    for (int j = 0; j < 8; j++) pr += pgen_cn[b * 8 + j] + pgen_co[b * 8 + j];
    float pg = fast_sigmoid(pr);
    *s_pg = pg;
    if (vt == 0) pgens_t[b] = pg;
  }
  __syncthreads();
  float pg = *s_pg;
  float M = rowMS[b * 2];
  float Sinv = __builtin_amdgcn_rcpf(rowMS[b * 2 + 1]);
  const float* lg = logits + (size_t)b * VV;
  float* dst = final_t + (size_t)b * VEXT;
  int v0 = vt * 2048 + tid * 8;
  if (v0 + 7 < VV){
    f32x4 x0 = *(const f32x4*)(lg + v0);
    f32x4 x1 = *(const f32x4*)(lg + v0 + 4);
    f32x2 y;
    y.x = pg * __expf(x0.x - M) * Sinv; y.y = pg * __expf(x0.y - M) * Sinv;
    __builtin_nontemporal_store(y, (f32x2*)(dst + v0));
    y.x = pg * __expf(x0.z - M) * Sinv; y.y = pg * __expf(x0.w - M) * Sinv;
    __builtin_nontemporal_store(y, (f32x2*)(dst + v0 + 2));
    y.x = pg * __expf(x1.x - M) * Sinv; y.y = pg * __expf(x1.y - M) * Sinv;
    __builtin_nontemporal_store(y, (f32x2*)(dst + v0 + 4));
    y.x = pg * __expf(x1.z - M) * Sinv; y.y = pg * __expf(x1.w - M) * Sinv;
    __builtin_nontemporal_store(y, (f32x2*)(dst + v0 + 6));
  } else {
    #pragma unroll
    for (int j = 0; j < 8; j++){
      int v = v0 + j;
      float val = (v < VV) ? pg * __expf(lg[v] - M) * Sinv : 0.f;
      if (v < VEXT) __builtin_nontemporal_store(val, dst + v);
    }
  }
}

__device__ __forceinline__ void scatter_unit(int u, int tid, const int* __restrict__ eidx,
    const float* __restrict__ attn_prev, const float* __restrict__ pgens_prev,
    float* __restrict__ final_prev)
{
  int i = u * 256 + tid;
  if (i >= 12800) return;
  int b = i / 400;
  float wv = (1.f - pgens_prev[b]) * attn_prev[i];
  atomicAdd(final_prev + (size_t)b * VEXT + eidx[i], wv);
}

// ---------------- P0: weight transposes (f32 -> bf16 NxK) + converts + pgen_emb + bar init ----
__device__ void transpose_bf16(const float* __restrict__ in, unsigned short* __restrict__ out,
                               int R, int C, int tile, float (*t)[65]){
  int tcn = C >> 6;
  int tr = tile / tcn, tc = tile - tr * tcn;
  int r0 = tr << 6, c0 = tc << 6;
  int cc = threadIdx.x & 63, rb = threadIdx.x >> 6;
  #pragma unroll
  for (int p = 0; p < 16; p++){
    int r = rb + p * 4;
    t[r][cc] = in[(size_t)(r0 + r) * C + (c0 + cc)];
  }
  __syncthreads();
  #pragma unroll
  for (int p = 0; p < 16; p++){
    int r = rb + p * 4;
    out[(size_t)(c0 + r) * R + (r0 + cc)] = f2bf(t[cc][r]);
  }
}

__global__ __launch_bounds__(256) void k_prep(
    const float* __restrict__ Wout, const float* __restrict__ Wg, const float* __restrict__ Ug,
    const float* __restrict__ W1, const float* __restrict__ W2, const float* __restrict__ enc,
    const float* __restrict__ dec_hidden, const int* __restrict__ dec_inp,
    const float* __restrict__ embedding, const float* __restrict__ Wp,
    unsigned short* WoutT, unsigned short* WgT, unsigned short* UgT,
    unsigned short* W1T, unsigned short* W2T, unsigned short* enc_bf,
    float* h0, unsigned short* h_bf, float* pgen_emb, unsigned* bar)
{
  __shared__ float tls[64][65];
  int b = blockIdx.x;
  int tid = threadIdx.x;
  if (b < 4000){ transpose_bf16(Wout, WoutT, 512, 32000, b, tls); return; }
  b -= 4000;
  if (b < 288){ transpose_bf16(Wg, WgT, 768, 1536, b, tls); return; }
  b -= 288;
  if (b < 192){ transpose_bf16(Ug, UgT, 512, 1536, b, tls); return; }
  b -= 192;
  if (b < 64){ transpose_bf16(W1, W1T, 512, 512, b, tls); return; }
  b -= 64;
  if (b < 64){ transpose_bf16(W2, W2T, 512, 512, b, tls); return; }
  b -= 64;
  if (b < 3200){
    size_t i0 = (size_t)b * 2048 + tid;
    #pragma unroll
    for (int p = 0; p < 8; p++){ size_t i = i0 + p * 256; enc_bf[i] = f2bf(enc[i]); }
    return;
  }
  b -= 3200;
  if (b < 8){
    size_t i0 = (size_t)b * 2048 + tid;
    #pragma unroll
    for (int p = 0; p < 8; p++){
      size_t i = i0 + p * 256; float v = dec_hidden[i];
      h0[i] = v; h_bf[i] = f2bf(v);
    }
    return;
  }
  b -= 8;
  if (b < 40){ // pgen_emb[t][b] = emb(t,b) . Wp[1024:1280]
    int t = b;
    int bb = tid >> 3, l8 = tid & 7;
    int tok = dec_inp[bb * 41 + t];
    const float* e = embedding + (size_t)tok * 256 + l8 * 32;
    const float* wp = Wp + 1024 + l8 * 32;
    float p = 0.f;
    #pragma unroll
    for (int j = 0; j < 32; j++) p += e[j] * wp[j];
    p += __shfl_xor(p, 1); p += __shfl_xor(p, 2); p += __shfl_xor(p, 4);
    if (l8 == 0) pgen_emb[t * 32 + bb] = p;
    return;
  }
  b -= 40;
  { // barrier init
    if (tid < 8) bar[tid] = 0u;
  }
}

// ---------------- P1: embW[t,b,:] = emb(t,b) @ Wg[0:256,:] + bg ----------------
__global__ __launch_bounds__(256) void k_embw(
    const int* __restrict__ dec_inp, const float* __restrict__ embedding,
    const unsigned short* __restrict__ WgT, const float* __restrict__ bg,
    float* __restrict__ embW)
{
  __shared__ unsigned short as[64 * 264];
  int blk = blockIdx.x;         // 20 m-tiles x 24 n-tiles
  int bm = blk / 24, bn = blk - bm * 24;
  int m0 = bm * 64, n0 = bn * 64;
  int tid = threadIdx.x;
  for (int i = tid; i < 64 * 256; i += 256){
    int r = i >> 8, c = i & 255;
    int R = m0 + r; int t = R >> 5, bb = R & 31;
    int tok = dec_inp[bb * 41 + t];
    as[r * 264 + c] = f2bf(embedding[(size_t)tok * 256 + c]);
  }
  __syncthreads();
  int lane = tid & 63, w = tid >> 6;
  int l15 = lane & 15, quad = lane >> 4;
  const unsigned short* arow = as + (w * 16 + l15) * 264 + quad * 8;
  f32x4 acc[4];
  #pragma unroll
  for (int i = 0; i < 4; i++) acc[i] = (f32x4)0.0f;
  for (int k0 = 0; k0 < 256; k0 += 32){
    bf16x8 a = *(const bf16x8*)(arow + k0);
    #pragma unroll
    for (int nt = 0; nt < 4; nt++){
      const unsigned short* brow = WgT + (size_t)(n0 + nt * 16 + l15) * 768 + k0 + quad * 8;
      acc[nt] = __builtin_amdgcn_mfma_f32_16x16x32_bf16(a, *(const bf16x8*)brow, acc[nt], 0, 0, 0);
    }
  }
  #pragma unroll
  for (int nt = 0; nt < 4; nt++){
    int col = n0 + nt * 16 + l15;
    float bias = bg[col];
    #pragma unroll
    for (int r = 0; r < 4; r++){
      int row = m0 + w * 16 + quad * 4 + r;
      embW[(size_t)row * 1536 + col] = acc[nt][r] + bias;
    }
  }
}

// ---------------- P2: enc_feat = enc_output @ W2 + b2 ----------------
__global__ __launch_bounds__(256) void k_encfeat(
    const unsigned short* __restrict__ enc_bf, const unsigned short* __restrict__ W2T,
    const float* __restrict__ b2, unsigned short* __restrict__ ef_bf)
{
  int blk = blockIdx.x;            // 200 x 8
  int bm = blk >> 3, bn = blk & 7;
  int lane = threadIdx.x & 63, w = threadIdx.x >> 6;
  int l15 = lane & 15, quad = lane >> 4;
  int m0 = bm * 64 + w * 16;
  int n0 = bn * 64;
  const unsigned short* arow = enc_bf + (size_t)(m0 + l15) * 512 + quad * 8;
  f32x4 acc[4];
  #pragma unroll
  for (int i = 0; i < 4; i++) acc[i] = (f32x4)0.0f;
  for (int k0 = 0; k0 < 512; k0 += 32){
    bf16x8 a = *(const bf16x8*)(arow + k0);
    #pragma unroll
    for (int nt = 0; nt < 4; nt++){
      const unsigned short* brow = W2T + (size_t)(n0 + nt * 16 + l15) * 512 + k0 + quad * 8;
      acc[nt] = __builtin_amdgcn_mfma_f32_16x16x32_bf16(a, *(const bf16x8*)brow, acc[nt], 0, 0, 0);
    }
  }
  #pragma unroll
  for (int nt = 0; nt < 4; nt++){
    int col = n0 + nt * 16 + l15;
    float bias = b2[col];
    #pragma unroll
    for (int r = 0; r < 4; r++){
      int row = m0 + quad * 4 + r;
      ef_bf[(size_t)row * 512 + col] = f2bf(acc[nt][r] + bias);
    }
  }
}

// ---------------- prologue: w1h(h0), scores(h0), attn0/ctx0 ----------------
__global__ __launch_bounds__(256) void k_w1h(
    const unsigned short* __restrict__ h_bf, const unsigned short* __restrict__ W1T,
    const float* __restrict__ b1, float* __restrict__ w1h)
{
  __shared__ char smem[33792];
  gemm_unit(threadIdx.x, (unsigned short*)smem, (float*)(smem + 33280),
            h_bf, W1T, b1, w1h, 512, blockIdx.x * 64, nullptr);
}

__global__ __launch_bounds__(256) void k_score_pro(
    const unsigned short* __restrict__ ef_bf, const float* __restrict__ w1h,
    const float* __restrict__ Wc, const float* __restrict__ Va, const float* __restrict__ bv,
    float* __restrict__ scores)
{
  __shared__ float sm[1536];
  score_unit(blockIdx.x / 25, blockIdx.x % 25, threadIdx.x, sm,
             ef_bf, w1h, Wc, Va, bv, nullptr, scores);
}

__global__ __launch_bounds__(256) void k_attn_pro(
    const float* __restrict__ scores, const float* __restrict__ mask,
    float* attn_out, float* cov_out, const unsigned short* __restrict__ enc_bf,
    float* __restrict__ ctx_out, const float* __restrict__ Wp,
    float* __restrict__ pgen_cn, float* __restrict__ pgen_co)
{
  __shared__ float sm[1024];
  attn_ctx_unit(blockIdx.x >> 3, blockIdx.x & 7, threadIdx.x, sm, sm + 512,
                scores, mask, nullptr, attn_out, cov_out, enc_bf, ctx_out, nullptr,
                Wp, pgen_cn, pgen_co);
}

// ---------------- the persistent megakernel: all 40 decode steps ----------------
struct MegaArgs {
  const unsigned short *WgT, *UgT, *WoutT, *W1T, *enc_bf, *ef_bf;
  unsigned short *h_bf;
  const float *embW, *pgen_emb, *bout, *b1, *Wc, *Va, *bv, *Wp, *bp, *mask;
  const int *eidx;
  float *logits, *tilems, *w1h, *scores, *rowMS, *pgen_hd, *pgen_cn, *pgen_co0, *pgen_co1;
  float *h0, *h1, *ctx0, *ctx1;
  float *final_, *attns, *covs, *hf, *ctxf, *pgens;
  unsigned *bar;
};

__global__ __launch_bounds__(256, 1) void k_mega(MegaArgs A){
  __shared__ char smem[33792];
  unsigned short* r0 = (unsigned short*)smem;
  float* smf = (float*)smem;
  float* smp = (float*)(smem + 33280);
  unsigned ep = 0;
  int blk = blockIdx.x, tid = threadIdx.x;
  for (int t = 0; t < 40; t++){
    int p = t & 1;
    const float* ctx_old = p ? A.ctx1 : A.ctx0;
    float* ctx_new       = p ? A.ctx0 : A.ctx1;
    const float* h_old   = p ? A.h1 : A.h0;
    float* h_new         = p ? A.h0 : A.h1;
    float* co_slot       = p ? A.pgen_co1 : A.pgen_co0;  // pgen_co[t&1]
    // ---- Phase A: GRU(t) on blocks 0..7 + final(t-1) on blocks 8..255 ----
    if (blk < 8){
      gru_block(blk, tid, r0, ctx_old, h_old, A.embW + (size_t)t * 49152,
                A.WgT, A.UgT, h_new, A.h_bf, (t == 39) ? A.hf : nullptr);
    } else if (t >= 1){
      const float* pe = A.pgen_emb + (t - 1) * 32;
      float* fin = A.final_ + (size_t)(t - 1) * 32 * VEXT;
      float* pgo = A.pgens + (t - 1) * 32;
      for (int u = blk - 8; u < 512; u += 248){
        final_dist_write(u, tid, smf, A.logits, A.rowMS, A.pgen_hd, A.pgen_cn,
                         co_slot, pe, A.bp, fin, pgo);
        __syncthreads();
      }
    }
    gbar(A.bar, ep);
    // ---- Phase B: logits (500) + w1h (8) + scatter(t-1) (50) over 256 blocks ----
    {
      int nunit = (t >= 1) ? 558 : 508;
      for (int u = blk; u < nunit; u += (int)NBLK){
        if (u < 500)
          gemm_unit(tid, r0, smp, A.h_bf, A.WoutT, A.bout, A.logits, VV, u * 64,
                    A.tilems + u * 64);
        else if (u < 508)
          gemm_unit(tid, r0, smp, A.h_bf, A.W1T, A.b1, A.w1h, 512, (u - 500) * 64, nullptr);
        else
          scatter_unit(u - 508, tid, A.eidx, A.attns + (size_t)(t - 1) * 12800,
                       A.pgens + (t - 1) * 32, A.final_ + (size_t)(t - 1) * 32 * VEXT);
      }
    }
    gbar(A.bar, ep);
    // ---- Phase C: scores (800) + pgen_hd (32) + rowMS (32) over 256 blocks ----
    for (int u = blk; u < 864; u += (int)NBLK){
      if (u < 800) score_unit(u / 25, u % 25, tid, smf, A.ef_bf, A.w1h, A.Wc, A.Va, A.bv,
                              A.covs + (size_t)t * 12800, A.scores);
      else if (u < 832) pgen_hd_unit(u - 800, tid, smf + 2048, h_new, A.Wp, A.pgen_hd);
      else rowms_unit(u - 832, tid, smf + 2048, A.tilems, A.rowMS);
    }
    gbar(A.bar, ep);
    // ---- Phase D: softmax/mask/renorm + attn/cov out + context + pgen ctx dots ----
    attn_ctx_unit(blk >> 3, blk & 7, tid, smf, smf + 512,
                  A.scores, A.mask, A.covs + (size_t)t * 12800,
                  (t < 39) ? A.attns + (size_t)(t + 1) * 12800 : nullptr,
                  (t < 39) ? A.covs + (size_t)(t + 1) * 12800 : nullptr,
                  A.enc_bf, ctx_new, (t == 39) ? A.ctxf : nullptr,
                  A.Wp, A.pgen_cn, co_slot);
    gbar(A.bar, ep);
  }
  // ---- epilogue: final(39) + scatter(39) ----
  {
    const float* pe = A.pgen_emb + 39 * 32;
    float* fin = A.final_ + (size_t)39 * 32 * VEXT;
    float* pgo = A.pgens + 39 * 32;
    for (int u = blk; u < 512; u += (int)NBLK){
      final_dist_write(u, tid, smf, A.logits, A.rowMS, A.pgen_hd, A.pgen_cn,
                       A.pgen_co0, pe, A.bp, fin, pgo);
      __syncthreads();
    }
  }
  gbar(A.bar, ep);
  if (blk < 50){
    scatter_unit(blk, tid, A.eidx, A.attns + (size_t)39 * 12800, A.pgens + 39 * 32,
                 A.final_ + (size_t)39 * 32 * VEXT);
  }
}

extern "C" void kernel_launch(void* const* d_in, const int* in_sizes, int n_in,
                              void* d_out, int out_size, void* d_ws, size_t ws_size,
                              hipStream_t stream) {
  const int*   dec_inp    = (const int*)d_in[0];
  const int*   eidx       = (const int*)d_in[1];
  const float* mask       = (const float*)d_in[2];
  const float* enc        = (const float*)d_in[4];
  const float* dec_hidden = (const float*)d_in[5];
  const float* embedding  = (const float*)d_in[6];
  const float* W1  = (const float*)d_in[7];
  const float* b1  = (const float*)d_in[8];
  const float* W2  = (const float*)d_in[9];
  const float* b2  = (const float*)d_in[10];
  const float* Wc  = (const float*)d_in[11];
  const float* Va  = (const float*)d_in[12];
  const float* bv  = (const float*)d_in[13];
  const float* Wg  = (const float*)d_in[14];
  const float* Ug  = (const float*)d_in[15];
  const float* bg  = (const float*)d_in[16];
  const float* Wout = (const float*)d_in[17];
  const float* bout = (const float*)d_in[18];
  const float* Wp  = (const float*)d_in[19];
  const float* bp  = (const float*)d_in[20];

  float* out    = (float*)d_out;
  float* final_ = out;                               // 40*32*32050
  float* attns  = out + (size_t)40 * 32 * VEXT;      // 40*32*400
  float* covs   = attns + 512000;
  float* hf     = covs + 512000;
  float* ctxf   = hf + 16384;
  float* pgens  = ctxf + 16384;

  char* wsb = (char*)d_ws; size_t off = 0;
  auto A = [&](size_t bytes)->char*{ char* p = wsb + off; off += (bytes + 255) & ~(size_t)255; return p; };
  float* logits   = (float*)A((size_t)32 * VV * 4);
  float* embW     = (float*)A((size_t)40 * 32 * 1536 * 4);
  float* tilems   = (float*)A(500 * 32 * 2 * 4);
  float* hbuf0    = (float*)A(65536);
  float* hbuf1    = (float*)A(65536);
  float* ctxbuf0  = (float*)A(65536);
  float* ctxbuf1  = (float*)A(65536);
  float* w1h      = (float*)A(65536);
  float* scores   = (float*)A(51200);
  float* rowMS    = (float*)A(256);
  float* pgen_hd  = (float*)A(128);
  float* pgen_cn  = (float*)A(1024);
  float* pgen_co0 = (float*)A(1024);
  float* pgen_co1 = (float*)A(1024);
  float* pgen_emb = (float*)A(40 * 32 * 4);
  unsigned* bar   = (unsigned*)A(256);
  unsigned short* h_bf   = (unsigned short*)A(32768);
  unsigned short* enc_bf = (unsigned short*)A((size_t)32 * 400 * 512 * 2);
  unsigned short* ef_bf  = (unsigned short*)A((size_t)32 * 400 * 512 * 2);
  unsigned short* W2T    = (unsigned short*)A(524288);
  unsigned short* W1T    = (unsigned short*)A(524288);
  unsigned short* WgT    = (unsigned short*)A(2359296);
  unsigned short* UgT    = (unsigned short*)A(1572864);
  unsigned short* WoutT  = (unsigned short*)A((size_t)VV * 512 * 2);

  // ---- prologue ----
  k_prep<<<7857, 256, 0, stream>>>(Wout, Wg, Ug, W1, W2, enc, dec_hidden, dec_inp, embedding, Wp,
                                   WoutT, WgT, UgT, W1T, W2T, enc_bf, hbuf0, h_bf, pgen_emb, bar);
  k_embw<<<480, 256, 0, stream>>>(dec_inp, embedding, WgT, bg, embW);
  k_encfeat<<<1600, 256, 0, stream>>>(enc_bf, W2T, b2, ef_bf);
  k_w1h<<<8, 256, 0, stream>>>(h_bf, W1T, b1, w1h);
  k_score_pro<<<800, 256, 0, stream>>>(ef_bf, w1h, Wc, Va, bv, scores);
  // attn0/cov0 -> outputs[0], ctx0 -> ctxbuf0, pgen_co1 = ctx0 . Wp[1280:] (for final(0))
  k_attn_pro<<<256, 256, 0, stream>>>(scores, mask, attns, covs, enc_bf,
                                      ctxbuf0, Wp, pgen_cn, pgen_co1);

  // ---- decode loop: one persistent launch, 256 blocks (guaranteed co-resident) ----
  MegaArgs m;
  m.WgT = WgT; m.UgT = UgT; m.WoutT = WoutT; m.W1T = W1T;
  m.enc_bf = enc_bf; m.ef_bf = ef_bf; m.h_bf = h_bf;
  m.embW = embW; m.pgen_emb = pgen_emb;
  m.bout = bout; m.b1 = b1; m.Wc = Wc; m.Va = Va; m.bv = bv; m.Wp = Wp; m.bp = bp; m.mask = mask;
  m.eidx = eidx;
  m.logits = logits; m.tilems = tilems; m.w1h = w1h; m.scores = scores; m.rowMS = rowMS;
  m.pgen_hd = pgen_hd; m.pgen_cn = pgen_cn; m.pgen_co0 = pgen_co0; m.pgen_co1 = pgen_co1;
  m.h0 = hbuf0; m.h1 = hbuf1; m.ctx0 = ctxbuf0; m.ctx1 = ctxbuf1;
  m.final_ = final_; m.attns = attns; m.covs = covs; m.hf = hf; m.ctxf = ctxf; m.pgens = pgens;
  m.bar = bar;
  k_mega<<<dim3(NBLK), dim3(256), 0, stream>>>(m);
}